// Round 2
// baseline (35648.862 us; speedup 1.0000x reference)
//
#include <hip/hip_runtime.h>
#include <math.h>

#pragma clang fp contract(off)

#define NS 1024
#define NU 8192
#define NPAIR (NU / 2)
#define FINF __builtin_huge_valf()

// ws layout (int units): [0] byteMode flag; [64..8255] order;
// [8256..41023] wl (floats, sorted workloads); [41024..303167] packed masks
#define WS_ORDER 64
#define WS_WL 8256
#define WS_PM 41024
#define WS_NEED_BYTES ((size_t)(WS_PM + NU * 32) * 4 + 256)

// ---------------------------------------------------------------------------
// Kernel 0: detect mask encoding. Words all in {0,1,0x3F800000} => 4-byte
// elements (int32 or float32). Anything else => 1-byte elements.
// ---------------------------------------------------------------------------
__global__ void detect_kernel(const unsigned* __restrict__ m, int* __restrict__ flag) {
    __shared__ int s_any;
    if (threadIdx.x == 0) s_any = 0;
    __syncthreads();
    int bad = 0;
    for (int i = threadIdx.x; i < 65536; i += 256) {
        unsigned v = m[i];
        bad |= !(v == 0u || v == 1u || v == 0x3F800000u);
    }
    if (bad) s_any = 1;   // benign same-value race
    __syncthreads();
    if (threadIdx.x == 0) flag[0] = s_any;
}

// ---------------------------------------------------------------------------
// Kernel 1: stable rank sort of users[:,2] -> order[rank] = i
// ---------------------------------------------------------------------------
__global__ void rank_kernel(const float* __restrict__ users, int* __restrict__ order) {
    __shared__ float keys[2048];
    const int i = blockIdx.x * 256 + threadIdx.x;
    const float key = users[i * 6 + 2];
    int rank = 0;
    for (int base = 0; base < NU; base += 2048) {
        __syncthreads();
        for (int k = threadIdx.x; k < 2048; k += 256)
            keys[k] = users[(base + k) * 6 + 2];
        __syncthreads();
        for (int k = 0; k < 2048; ++k) {
            float kj = keys[k];
            int j = base + k;
            rank += (kj < key) || ((kj == key) && (j < i));
        }
    }
    order[rank] = i;
}

// ---------------------------------------------------------------------------
// Kernel 1b: gather workloads in sorted order: wl[stp] = users[order[stp], 2:6]
// ---------------------------------------------------------------------------
__global__ void gather_kernel(const float* __restrict__ users, const int* __restrict__ order,
                              float* __restrict__ wl) {
    const int stp = blockIdx.x * 256 + threadIdx.x;
    const int u = order[stp];
    float2 a = *(const float2*)(users + u * 6 + 2);
    float2 b = *(const float2*)(users + u * 6 + 4);
    *(float4*)(wl + stp * 4) = make_float4(a.x, a.y, b.x, b.y);
}

// ---------------------------------------------------------------------------
// Kernel 1c: pack masks to 1 bit/server, in sorted user order.
// pm[stp*32 + w] bit b = mask[order[stp]*NS + 32w + b] != 0
// ---------------------------------------------------------------------------
__global__ void pack_kernel(const void* __restrict__ masksv, const int* __restrict__ wsi,
                            const int* __restrict__ order, unsigned* __restrict__ pm) {
    const int idx = blockIdx.x * 256 + threadIdx.x;
    const int stp = idx >> 5, w = idx & 31;
    const int u = order[stp];
    const int byteMode = wsi[0];
    unsigned word = 0;
    if (byteMode) {
        const uint4* q = (const uint4*)((const unsigned char*)masksv + (size_t)u * NS + w * 32);
        uint4 a = q[0], b = q[1];
        unsigned vv[8] = {a.x, a.y, a.z, a.w, b.x, b.y, b.z, b.w};
        #pragma unroll
        for (int d = 0; d < 8; ++d) {
            #pragma unroll
            for (int i = 0; i < 4; ++i)
                if ((vv[d] >> (8 * i)) & 0xFFu) word |= 1u << (d * 4 + i);
        }
    } else {
        const int4* q = (const int4*)((const int*)masksv + (size_t)u * NS + w * 32);
        #pragma unroll
        for (int d = 0; d < 8; ++d) {
            int4 v = q[d];
            if (v.x) word |= 1u << (d * 4 + 0);
            if (v.y) word |= 1u << (d * 4 + 1);
            if (v.z) word |= 1u << (d * 4 + 2);
            if (v.w) word |= 1u << (d * 4 + 3);
        }
    }
    pm[idx] = word;
}

// ---------------------------------------------------------------------------
// Kernel 2: sequential allocator. 1 block x 256 threads, 4 servers/thread.
// 2 barriers/step; masks+workloads prefetched 2 steps ahead from L2.
// ---------------------------------------------------------------------------
template <bool PACKED>
__global__ __launch_bounds__(256, 1)
void alloc_kernel(const float* __restrict__ servers,
                  const float* __restrict__ users,
                  const void*  __restrict__ masksv,
                  const int*   __restrict__ wsi,
                  float* __restrict__ out) {
    const int tid  = threadIdx.x;
    const int lane = tid & 63;
    const int wid  = tid >> 6;
    const int byteMode = wsi[0];
    const int* __restrict__ order_g = wsi + WS_ORDER;
    const float* __restrict__ wlf = (const float*)(wsi + WS_WL);
    const unsigned* __restrict__ pm = (const unsigned*)(wsi + WS_PM);
    const unsigned char* __restrict__ mbytes = (const unsigned char*)masksv;
    const int*           __restrict__ mwords = (const int*)masksv;

    __shared__ int   s_order[NU];
    __shared__ float rA[2][4][8];
    __shared__ float rM[4][8];

    for (int i = tid; i < NU; i += 256) s_order[i] = order_g[i];

    // per-thread state: servers sbase..sbase+3
    float c[4][4], t[4][4], f[4][4], B[4], us[4];
    const int sbase = tid * 4;
    #pragma unroll
    for (int j = 0; j < 4; ++j) {
        #pragma unroll
        for (int k = 0; k < 4; ++k) {
            float cv = servers[(sbase + j) * 7 + 3 + k];
            c[j][k] = cv;
            t[j][k] = cv;
            f[j][k] = 0.0f;
        }
        us[j] = 0.0f;
        B[j]  = 0.0f;
    }
    __syncthreads();             // s_order ready

    float allocCnt = 0.0f;       // tid 0 only

    auto load_one = [&](int stp, unsigned& mraw, float4& wl4) {
        if (PACKED) {
            mraw = pm[stp * 32 + (tid >> 3)];
            wl4  = *(const float4*)(wlf + stp * 4);
        } else {
            int u = s_order[stp];
            if (byteMode) {
                uchar4 mv = *(const uchar4*)(mbytes + (size_t)u * NS + sbase);
                mraw = (mv.x ? 1u : 0u) | (mv.y ? 2u : 0u) | (mv.z ? 4u : 0u) | (mv.w ? 8u : 0u);
            } else {
                int4 mv = *(const int4*)(mwords + (size_t)u * NS + sbase);
                mraw = (mv.x ? 1u : 0u) | (mv.y ? 2u : 0u) | (mv.z ? 4u : 0u) | (mv.w ? 8u : 0u);
            }
            float2 a = *(const float2*)(users + u * 6 + 2);
            float2 b = *(const float2*)(users + u * 6 + 4);
            wl4 = make_float4(a.x, a.y, b.x, b.y);
        }
    };

    auto do_step = [&](int stp, unsigned mraw, float4 wl) {
        const float w0 = wl.x, w1 = wl.y, w2 = wl.z, w3 = wl.w;
        const int mcur = PACKED ? (int)((mraw >> ((tid & 7) * 4)) & 0xFu) : (int)mraw;
        const int par = stp & 1;

        // ---- phase A: valid, sum(fuzzy), count, minmax(B), C flags
        int   vbits = 0;
        float sumF = 0.0f, cnt = 0.0f;
        float mxB = -FINF, mnB = FINF;
        int   aC10 = 0, aC0 = 0;
        #pragma unroll
        for (int j = 0; j < 4; ++j) {
            bool valid = ((mcur >> j) & 1) &&
                         (t[j][0] >= w0) && (t[j][1] >= w1) &&
                         (t[j][2] >= w2) && (t[j][3] >= w3);
            if (valid) {
                vbits |= 1 << j;
                sumF += f[j][0] + f[j][1] + f[j][2] + f[j][3];
                cnt  += 1.0f;
                mxB = fmaxf(mxB, B[j]);
                mnB = fminf(mnB, B[j]);
                if (us[j] == 0.0f) aC10 = 1; else aC0 = 1;
            }
        }
        #pragma unroll
        for (int off = 32; off > 0; off >>= 1) {
            sumF += __shfl_xor(sumF, off);
            cnt  += __shfl_xor(cnt, off);
            mxB = fmaxf(mxB, __shfl_xor(mxB, off));
            mnB = fminf(mnB, __shfl_xor(mnB, off));
        }
        unsigned long long b10 = __ballot(aC10);
        unsigned long long b0  = __ballot(aC0);
        if (lane == 0) {
            rA[par][wid][0] = sumF; rA[par][wid][1] = cnt;
            rA[par][wid][2] = mxB;  rA[par][wid][3] = mnB;
            rA[par][wid][4] = b10 ? 1.0f : 0.0f;
            rA[par][wid][5] = b0  ? 1.0f : 0.0f;
        }
        __syncthreads();   // B1
        sumF = rA[par][0][0] + rA[par][1][0] + rA[par][2][0] + rA[par][3][0];
        cnt  = rA[par][0][1] + rA[par][1][1] + rA[par][2][1] + rA[par][3][1];
        mxB  = fmaxf(fmaxf(rA[par][0][2], rA[par][1][2]), fmaxf(rA[par][2][2], rA[par][3][2]));
        mnB  = fminf(fminf(rA[par][0][3], rA[par][1][3]), fminf(rA[par][2][3], rA[par][3][3]));
        bool hasC10 = (rA[par][0][4] + rA[par][1][4] + rA[par][2][4] + rA[par][3][4]) > 0.0f;
        bool hasC0  = (rA[par][0][5] + rA[par][1][5] + rA[par][2][5] + rA[par][3][5]) > 0.0f;

        float alloc = -1.0f;
        if (cnt > 0.0f) {
            // row is known from mean; only col (3 tw candidates) is pending on var.
            float n = cnt * 4.0f;
            float mean = sumF / fmaxf(n, 1.0f);
            int row = (mean <= 0.2f) ? 0 : ((mean <= 0.5f) ? 1 : 2);
            float tw_[3];
            if (row == 0)      { tw_[0] = 0.9f; tw_[1] = 0.8f; tw_[2] = 0.6f; }
            else if (row == 1) { tw_[0] = 0.6f; tw_[1] = 0.5f; tw_[2] = 0.4f; }
            else               { tw_[0] = 0.4f; tw_[1] = 0.2f; tw_[2] = 0.1f; }
            float mxC = hasC10 ? 10.0f : 0.0f;
            float mnC = hasC0  ? 0.0f  : 10.0f;
            float dB = mxB - mnB;
            float dC = mxC - mnC;
            float ci10 = (dC != 0.0f) ? (10.0f - mnC) / dC : 0.0f;
            float ci0  = (dC != 0.0f) ? (0.0f  - mnC) / dC : 0.0f;
            float aH[3], b10H[3], b0H[3];
            #pragma unroll
            for (int h = 0; h < 3; ++h) {
                float tw = tw_[h];
                aH[h] = tw + 0.3f;
                float bb = (1.0f - tw) + 0.55f;   // exact same expr as reference path
                b10H[h] = bb * ci10;
                b0H[h]  = bb * ci0;
            }

            // ---- fused phase B+C: var partials + 3-hypothesis argmin partials
            float s2 = 0.0f;
            float bV[3] = {FINF, FINF, FINF};
            int   bI[3] = {NS, NS, NS};
            #pragma unroll
            for (int j = 0; j < 4; ++j) {
                bool valid = (vbits >> j) & 1;
                if (valid) {
                    float d0 = f[j][0] - mean;
                    float d1 = f[j][1] - mean;
                    float d2 = f[j][2] - mean;
                    float d3 = f[j][3] - mean;
                    s2 += d0 * d0 + d1 * d1 + d2 * d2 + d3 * d3;
                }
                float bi = (dB != 0.0f) ? (B[j] - mnB) / dB : 0.0f;
                int idx = sbase + j;
                #pragma unroll
                for (int h = 0; h < 3; ++h) {
                    float sc = aH[h] * bi + ((us[j] == 0.0f) ? b10H[h] : b0H[h]);
                    float key = valid ? sc : FINF;
                    if (key < bV[h] || (key == bV[h] && idx < bI[h])) { bV[h] = key; bI[h] = idx; }
                }
            }
            #pragma unroll
            for (int off = 32; off > 0; off >>= 1) {
                s2 += __shfl_xor(s2, off);
                #pragma unroll
                for (int h = 0; h < 3; ++h) {
                    float ov = __shfl_xor(bV[h], off);
                    int   oi = __shfl_xor(bI[h], off);
                    if (ov < bV[h] || (ov == bV[h] && oi < bI[h])) { bV[h] = ov; bI[h] = oi; }
                }
            }
            if (lane == 0) {
                rM[wid][0] = s2;
                #pragma unroll
                for (int h = 0; h < 3; ++h) {
                    rM[wid][1 + 2 * h] = bV[h];
                    rM[wid][2 + 2 * h] = __int_as_float(bI[h]);
                }
            }
            __syncthreads();   // B2
            s2 = rM[0][0] + rM[1][0] + rM[2][0] + rM[3][0];
            float var = s2 / fmaxf(n - 1.0f, 1.0f);
            float sd  = sqrtf(var);
            int col = (sd <= 0.1f) ? 0 : ((sd <= 0.3f) ? 1 : 2);
            // cross-wave combine of the selected hypothesis (LDS dynamic idx OK)
            float bestV = rM[0][1 + 2 * col];
            int   bestI = __float_as_int(rM[0][2 + 2 * col]);
            #pragma unroll
            for (int w = 1; w < 4; ++w) {
                float ov = rM[w][1 + 2 * col];
                int   oi = __float_as_int(rM[w][2 + 2 * col]);
                if (ov < bestV || (ov == bestV && oi < bestI)) { bestV = ov; bestI = oi; }
            }
            const int chosen = bestI;
            alloc = (float)chosen;

            // ---- update chosen server (static register indexing)
            #pragma unroll
            for (int j = 0; j < 4; ++j) {
                if (sbase + j == chosen) {
                    t[j][0] = t[j][0] - w0;
                    t[j][1] = t[j][1] - w1;
                    t[j][2] = t[j][2] - w2;
                    t[j][3] = t[j][3] - w3;
                    us[j] = us[j] + 1.0f;
                    #pragma unroll
                    for (int k = 0; k < 4; ++k) {
                        const float mid  = (k == 0) ? 0.4f : ((k == 1) ? 0.5f : ((k == 2) ? 0.3f : 0.5f));
                        const float high = (k == 0) ? 0.8f : ((k == 1) ? 0.8f : ((k == 2) ? 0.7f : 0.8f));
                        float rem = c[j][k] - t[j][k];
                        float x = rem / c[j][k];
                        float fv;
                        if (x <= 0.0f)      fv = 0.0f;
                        else if (x <= mid)  fv = x / mid;
                        else if (x <= high) fv = (high - x) / (high - mid);
                        else                fv = 0.0f;
                        f[j][k] = fv;
                    }
                    float sB = t[j][0] / c[j][0] + t[j][1] / c[j][1]
                             + t[j][2] / c[j][2] + t[j][3] / c[j][3];
                    B[j] = 1.0f - sB * 0.25f;
                }
            }
        }
        // no barrier needed in the skip path: rA is parity double-buffered,
        // rM writes are fenced by the next step's B1.

        if (tid == 0) {
            int uid = s_order[stp];
            out[uid] = alloc;
            if (alloc != -1.0f) allocCnt += 1.0f;
        }
    };

    // 2-step (pair) software pipeline: prefetch pair p+1 while computing pair p
    unsigned m0, m1;
    float4 q0, q1;
    load_one(0, m0, q0);
    load_one(1, m1, q1);
    for (int p = 0; p < NPAIR; ++p) {
        unsigned n0 = 0, n1 = 0;
        float4 r0 = q0, r1 = q1;
        if (p + 1 < NPAIR) {
            load_one(2 * p + 2, n0, r0);
            load_one(2 * p + 3, n1, r1);
        }
        do_step(2 * p,     m0, q0);
        do_step(2 * p + 1, m1, q1);
        m0 = n0; q0 = r0;
        m1 = n1; q1 = r1;
    }

    __syncthreads();   // protect rM reuse below vs last step's reads
    #pragma unroll
    for (int j = 0; j < 4; ++j) out[NU + sbase + j] = us[j];
    float uc = 0.0f;
    #pragma unroll
    for (int j = 0; j < 4; ++j) uc += (us[j] != 0.0f) ? 1.0f : 0.0f;
    #pragma unroll
    for (int off = 32; off > 0; off >>= 1) uc += __shfl_xor(uc, off);
    if (lane == 0) rM[wid][0] = uc;
    __syncthreads();
    if (tid == 0) {
        float ut = rM[0][0] + rM[1][0] + rM[2][0] + rM[3][0];
        out[NU + NS]     = allocCnt / 8192.0f;
        out[NU + NS + 1] = ut / 1024.0f;
    }
}

// ---------------------------------------------------------------------------
extern "C" void kernel_launch(void* const* d_in, const int* in_sizes, int n_in,
                              void* d_out, int out_size, void* d_ws, size_t ws_size,
                              hipStream_t stream) {
    const float* servers = (const float*)d_in[0];
    const float* users   = (const float*)d_in[1];
    const void*  masks   = d_in[2];
    int*   wsi = (int*)d_ws;
    float* out = (float*)d_out;

    detect_kernel<<<1, 256, 0, stream>>>((const unsigned*)masks, wsi);
    rank_kernel<<<32, 256, 0, stream>>>(users, wsi + WS_ORDER);
    if (ws_size >= WS_NEED_BYTES) {
        gather_kernel<<<NU / 256, 256, 0, stream>>>(users, wsi + WS_ORDER, (float*)(wsi + WS_WL));
        pack_kernel<<<NU * 32 / 256, 256, 0, stream>>>(masks, wsi, wsi + WS_ORDER,
                                                       (unsigned*)(wsi + WS_PM));
        alloc_kernel<true><<<1, 256, 0, stream>>>(servers, users, masks, wsi, out);
    } else {
        alloc_kernel<false><<<1, 256, 0, stream>>>(servers, users, masks, wsi, out);
    }
}